// Round 4
// baseline (57.261 us; speedup 1.0000x reference)
//
#include <hip/hip_runtime.h>

#define G_ 1024
#define DIN_ 3072
#define B_ 8192
#define TB 2          // rows per LDS buffer (24 KiB)
#define RT 4          // tiles per block (persistence, amortizes cold prologue)
#define TPB 256
#define GPT 4         // groups per thread

// ---------------------------------------------------------------------------
// Kernel 1: per-group coefficient precompute.
// out[b,g,m] = K + cx0*x0 + cx1*x1 + cx2*x2 + cq01*x0x1 + cq02*x0x2 + cq12*x1x2
// (gating + softmax + all 6 permutations folded into 7 coeffs per (g,m)).
// coef layout: coef[g*24 + m*8 + {0..6}]  (float4-friendly stride 8)
// ---------------------------------------------------------------------------
__global__ __launch_bounds__(256) void fredkin_coef_kernel(
    const int* __restrict__ conn, const float* __restrict__ sel,
    const float* __restrict__ wg, float* __restrict__ coef)
{
    int g = blockIdx.x * blockDim.x + threadIdx.x;
    if (g >= G_) return;

    float u[3], v[3];
#pragma unroll
    for (int i = 0; i < 3; ++i) {
        float s = sel[g * 3 + i];
        float C = s / (1.0f + fabsf(s));
        float a = fabsf(C);
        u[i] = 1.0f - a;          // multiplier on x
        v[i] = 0.5f * (C + a);    // additive bias
    }

    float w[6];
    float mx = -1e30f;
#pragma unroll
    for (int p = 0; p < 6; ++p) mx = fmaxf(mx, wg[g * 6 + p]);
    float sum = 0.0f;
#pragma unroll
    for (int p = 0; p < 6; ++p) { w[p] = expf(wg[g * 6 + p] - mx); sum += w[p]; }
    float inv = 1.0f / sum;
#pragma unroll
    for (int p = 0; p < 6; ++p) w[p] *= inv;

    // itertools.permutations(range(3)) order
    const int P[6][3] = {{0,1,2},{0,2,1},{1,0,2},{1,2,0},{2,0,1},{2,1,0}};
    // signal_0 = a ; signal_1 = c + ab - ac ; signal_2 = b - ab + ac
    float L[3][3] = {{0.f,0.f,0.f},{0.f,0.f,0.f},{0.f,0.f,0.f}};
    float Q[3][3] = {{0.f,0.f,0.f},{0.f,0.f,0.f},{0.f,0.f,0.f}};
#pragma unroll
    for (int p = 0; p < 6; ++p) {
        int i0 = P[p][0], i1 = P[p][1], i2 = P[p][2];
        float wp = w[p];
        int p01 = i0 + i1 - 1;   // pair idx (i,j)->i+j-1 for i<j
        int p02 = i0 + i2 - 1;
        L[0][i0] += wp;                                   // m0
        L[1][i2] += wp; Q[1][p01] += wp; Q[1][p02] -= wp; // m1
        L[2][i1] += wp; Q[2][p01] -= wp; Q[2][p02] += wp; // m2
    }

#pragma unroll
    for (int m = 0; m < 3; ++m) {
        float K = L[m][0]*v[0] + L[m][1]*v[1] + L[m][2]*v[2]
                + Q[m][0]*v[0]*v[1] + Q[m][1]*v[0]*v[2] + Q[m][2]*v[1]*v[2];
        float cx0 = u[0]*(L[m][0] + Q[m][0]*v[1] + Q[m][1]*v[2]);
        float cx1 = u[1]*(L[m][1] + Q[m][0]*v[0] + Q[m][2]*v[2]);
        float cx2 = u[2]*(L[m][2] + Q[m][1]*v[0] + Q[m][2]*v[1]);
        float* om = coef + (size_t)g * 24 + m * 8;
        om[0]=K; om[1]=cx0; om[2]=cx1; om[3]=cx2;
        om[4]=Q[m][0]*u[0]*u[1]; om[5]=Q[m][1]*u[0]*u[2]; om[6]=Q[m][2]*u[1]*u[2];
        om[7]=0.f;
    }
}

// ---------------------------------------------------------------------------
// Kernel 2: 2-phase double-buffered streaming evaluation.
//   prologue: STAGE(buf0, tile0); barrier;
//   loop t:   STAGE(buf[t^1], tile t+1);   // issued BEFORE compute
//             compute from buf[t];          // stage latency hides here
//             barrier;                      // vmcnt drain overlapped by compute
// 2 x 24 KiB buffers -> 48 KiB LDS -> 3 blocks/CU; __launch_bounds__(256,3)
// pins VGPR <= ~170 so LDS stays the occupancy cap (12 waves/CU).
// Output stores are non-temporal (write-once stream; keeps x L3-resident).
// ---------------------------------------------------------------------------
__global__ __launch_bounds__(TPB, 3) void fredkin_main_kernel(
    const float* __restrict__ x, const int* __restrict__ conn,
    const float* __restrict__ coef, float* __restrict__ out)
{
    __shared__ float xs[2][TB * DIN_];   // 2 x 24 KiB
    const int t = threadIdx.x;

    // conn indices for this thread's 4 groups: registers for the whole block
    int c0[GPT], c1[GPT], c2[GPT];
#pragma unroll
    for (int gi = 0; gi < GPT; ++gi) {
        const int g = t + gi * TPB;
        c0[gi] = conn[g * 3 + 0];
        c1[gi] = conn[g * 3 + 1];
        c2[gi] = conn[g * 3 + 2];
    }

    const int tile0 = blockIdx.x * RT;

    // prologue: stage tile0 into buffer 0 (6 x 16B per thread, linear LDS)
    {
        const float4* xv = (const float4*)(x + (size_t)tile0 * TB * DIN_);
        float4* sv = (float4*)xs[0];
#pragma unroll
        for (int i = 0; i < (TB * DIN_ / 4) / TPB; ++i)
            __builtin_amdgcn_global_load_lds(
                (const __attribute__((address_space(1))) void*)(xv + t + i * TPB),
                (__attribute__((address_space(3))) void*)(sv + t + i * TPB),
                16, 0, 0);
    }
    __syncthreads();

    for (int tt = 0; tt < RT; ++tt) {
        const int cur = tt & 1;

        // issue next tile's stage FIRST -- its latency hides under compute
        if (tt + 1 < RT) {
            const float4* xv =
                (const float4*)(x + (size_t)(tile0 + tt + 1) * TB * DIN_);
            float4* sv = (float4*)xs[cur ^ 1];
#pragma unroll
            for (int i = 0; i < (TB * DIN_ / 4) / TPB; ++i)
                __builtin_amdgcn_global_load_lds(
                    (const __attribute__((address_space(1))) void*)(xv + t + i * TPB),
                    (__attribute__((address_space(3))) void*)(sv + t + i * TPB),
                    16, 0, 0);
        }

        const float* xb = xs[cur];
        const int row0 = (tile0 + tt) * TB;
#pragma unroll
        for (int gi = 0; gi < GPT; ++gi) {
            const int g = t + gi * TPB;
            const float4* cf = (const float4*)(coef + (size_t)g * 24);
            const float4 a0 = cf[0], q0 = cf[1];
            const float4 a1 = cf[2], q1 = cf[3];
            const float4 a2 = cf[4], q2 = cf[5];
            // all gathers independent, issued together
            float g0[TB], g1[TB], g2[TB];
#pragma unroll
            for (int r = 0; r < TB; ++r) {
                g0[r] = xb[r * DIN_ + c0[gi]];
                g1[r] = xb[r * DIN_ + c1[gi]];
                g2[r] = xb[r * DIN_ + c2[gi]];
            }
#pragma unroll
            for (int r = 0; r < TB; ++r) {
                const float x0 = g0[r], x1 = g1[r], x2 = g2[r];
                const float p01 = x0 * x1, p02 = x0 * x2, p12 = x1 * x2;
                float o0 = a0.x + a0.y*x0 + a0.z*x1 + a0.w*x2 + q0.x*p01 + q0.y*p02 + q0.z*p12;
                float o1 = a1.x + a1.y*x0 + a1.z*x1 + a1.w*x2 + q1.x*p01 + q1.y*p02 + q1.z*p12;
                float o2 = a2.x + a2.y*x0 + a2.z*x1 + a2.w*x2 + q2.x*p01 + q2.y*p02 + q2.z*p12;
                float* op = out + (size_t)(row0 + r) * (3 * G_) + 3 * g;
                __builtin_nontemporal_store(o0, op + 0);
                __builtin_nontemporal_store(o1, op + 1);
                __builtin_nontemporal_store(o2, op + 2);
            }
        }
        if (tt + 1 < RT) __syncthreads();   // WAR guard + drains next stage
    }
}

extern "C" void kernel_launch(void* const* d_in, const int* in_sizes, int n_in,
                              void* d_out, int out_size, void* d_ws, size_t ws_size,
                              hipStream_t stream) {
    const float* x    = (const float*)d_in[0];
    const int*   conn = (const int*)d_in[1];
    const float* sel  = (const float*)d_in[2];
    const float* wg   = (const float*)d_in[3];
    float* out  = (float*)d_out;
    float* coef = (float*)d_ws;   // G_*24 floats = 96 KiB

    hipLaunchKernelGGL(fredkin_coef_kernel, dim3(G_ / 256), dim3(256), 0, stream,
                       conn, sel, wg, coef);
    hipLaunchKernelGGL(fredkin_main_kernel, dim3(B_ / (TB * RT)), dim3(TPB), 0, stream,
                       x, conn, coef, out);
}

// Round 5
// 39.000 us; speedup vs baseline: 1.4682x; 1.4682x over previous
//
#include <hip/hip_runtime.h>

#define G_ 1024
#define DIN_ 3072
#define B_ 8192
#define TB 4          // rows staged per block (48 KiB LDS)
#define TPB 512
#define GPT 2         // consecutive groups per thread

// ---------------------------------------------------------------------------
// Fused single kernel.
// out[b,g,m] = K + cx0*x0 + cx1*x1 + cx2*x2 + cq01*x0x1 + cq02*x0x2 + cq12*x1x2
// where x_i = x[b, conn[g,i]] and the 7 coeffs per (g,m) fold the soft-gate,
// the 6 Fredkin permutations, and the softmax weights.
//
// Schedule per block:
//   1) issue 6x global_load_lds (TB rows -> 48 KiB LDS, linear dest)
//   2) recompute 2 groups' coefficients in registers  <- covers stage latency
//   3) __syncthreads (vmcnt drain is cheap: loads arrived under phase 2)
//   4) 4 rows x { 6 LDS gathers, 42 FMA, 24 B contiguous store }
// 512 thr, ~90-110 VGPR, 48 KiB LDS -> 2 blocks/CU = 16 waves/CU.
// ---------------------------------------------------------------------------
__global__ __launch_bounds__(TPB, 4) void fredkin_fused_kernel(
    const float* __restrict__ x, const int* __restrict__ conn,
    const float* __restrict__ sel, const float* __restrict__ wg,
    float* __restrict__ out)
{
    __shared__ float xs[TB * DIN_];   // 48 KiB
    const int t = threadIdx.x;
    const int row0 = blockIdx.x * TB;

    // ---- phase 1: issue direct-to-LDS stage (6 x 16 B per thread) ----
    const float4* xv = (const float4*)(x + (size_t)row0 * DIN_);
    float4* sv = (float4*)xs;
#pragma unroll
    for (int i = 0; i < (TB * DIN_ / 4) / TPB; ++i)   // 6 iters
        __builtin_amdgcn_global_load_lds(
            (const __attribute__((address_space(1))) void*)(xv + t + i * TPB),
            (__attribute__((address_space(3))) void*)(sv + t + i * TPB),
            16, 0, 0);

    // ---- phase 2: coefficient recompute for GPT consecutive groups ----
    int   cc[GPT][3];
    float CF[GPT][3][7];   // per m: K, cx0, cx1, cx2, cq01, cq02, cq12
#pragma unroll
    for (int gi = 0; gi < GPT; ++gi) {
        const int g = t * GPT + gi;

        float u[3], v[3];
#pragma unroll
        for (int i = 0; i < 3; ++i) {
            cc[gi][i] = conn[g * 3 + i];
            float s = sel[g * 3 + i];
            float C = s / (1.0f + fabsf(s));
            float a = fabsf(C);
            u[i] = 1.0f - a;
            v[i] = 0.5f * (C + a);
        }

        // softmax over 6 permutation weights (hardware exp; threshold 0.18)
        float w[6];
        float mx = -1e30f;
#pragma unroll
        for (int p = 0; p < 6; ++p) mx = fmaxf(mx, wg[g * 6 + p]);
        float sum = 0.0f;
#pragma unroll
        for (int p = 0; p < 6; ++p) { w[p] = __expf(wg[g * 6 + p] - mx); sum += w[p]; }
        float inv = 1.0f / sum;
#pragma unroll
        for (int p = 0; p < 6; ++p) w[p] *= inv;

        // itertools.permutations(range(3)); signals:
        // m0 = a ; m1 = c + ab - ac ; m2 = b - ab + ac   (a,b,c = permuted gated)
        const int P[6][3] = {{0,1,2},{0,2,1},{1,0,2},{1,2,0},{2,0,1},{2,1,0}};
        float L[3][3] = {{0.f,0.f,0.f},{0.f,0.f,0.f},{0.f,0.f,0.f}};
        float Q[3][3] = {{0.f,0.f,0.f},{0.f,0.f,0.f},{0.f,0.f,0.f}};
#pragma unroll
        for (int p = 0; p < 6; ++p) {
            int i0 = P[p][0], i1 = P[p][1], i2 = P[p][2];
            float wp = w[p];
            int p01 = i0 + i1 - 1;   // pair idx (i,j)->i+j-1, i<j
            int p02 = i0 + i2 - 1;
            L[0][i0] += wp;
            L[1][i2] += wp; Q[1][p01] += wp; Q[1][p02] -= wp;
            L[2][i1] += wp; Q[2][p01] -= wp; Q[2][p02] += wp;
        }

        // substitute gated_i = u_i*x_i + v_i -> x-space coefficients
#pragma unroll
        for (int m = 0; m < 3; ++m) {
            CF[gi][m][0] = L[m][0]*v[0] + L[m][1]*v[1] + L[m][2]*v[2]
                         + Q[m][0]*v[0]*v[1] + Q[m][1]*v[0]*v[2] + Q[m][2]*v[1]*v[2];
            CF[gi][m][1] = u[0]*(L[m][0] + Q[m][0]*v[1] + Q[m][1]*v[2]);
            CF[gi][m][2] = u[1]*(L[m][1] + Q[m][0]*v[0] + Q[m][2]*v[2]);
            CF[gi][m][3] = u[2]*(L[m][2] + Q[m][1]*v[0] + Q[m][2]*v[1]);
            CF[gi][m][4] = Q[m][0]*u[0]*u[1];
            CF[gi][m][5] = Q[m][1]*u[0]*u[2];
            CF[gi][m][6] = Q[m][2]*u[1]*u[2];
        }
    }

    // ---- phase 3: barrier (stage already landed under phase 2) ----
    __syncthreads();

    // ---- phase 4: evaluate TB rows ----
#pragma unroll
    for (int r = 0; r < TB; ++r) {
        const float* xb = xs + r * DIN_;
        // all 6 gathers independent, issued together
        float gx[GPT][3];
#pragma unroll
        for (int gi = 0; gi < GPT; ++gi) {
            gx[gi][0] = xb[cc[gi][0]];
            gx[gi][1] = xb[cc[gi][1]];
            gx[gi][2] = xb[cc[gi][2]];
        }
        float o[GPT * 3];
#pragma unroll
        for (int gi = 0; gi < GPT; ++gi) {
            const float x0 = gx[gi][0], x1 = gx[gi][1], x2 = gx[gi][2];
            const float p01 = x0 * x1, p02 = x0 * x2, p12 = x1 * x2;
#pragma unroll
            for (int m = 0; m < 3; ++m) {
                o[gi * 3 + m] = CF[gi][m][0]
                              + CF[gi][m][1]*x0 + CF[gi][m][2]*x1 + CF[gi][m][3]*x2
                              + CF[gi][m][4]*p01 + CF[gi][m][5]*p02 + CF[gi][m][6]*p12;
            }
        }
        // 24 B contiguous per lane -> wave writes 1536 B contiguous
        float2* op = (float2*)(out + (size_t)(row0 + r) * (3 * G_) + (size_t)t * (3 * GPT));
        op[0] = make_float2(o[0], o[1]);
        op[1] = make_float2(o[2], o[3]);
        op[2] = make_float2(o[4], o[5]);
    }
}

extern "C" void kernel_launch(void* const* d_in, const int* in_sizes, int n_in,
                              void* d_out, int out_size, void* d_ws, size_t ws_size,
                              hipStream_t stream) {
    const float* x    = (const float*)d_in[0];
    const int*   conn = (const int*)d_in[1];
    const float* sel  = (const float*)d_in[2];
    const float* wg   = (const float*)d_in[3];
    float* out = (float*)d_out;

    hipLaunchKernelGGL(fredkin_fused_kernel, dim3(B_ / TB), dim3(TPB), 0, stream,
                       x, conn, sel, wg, out);
}